// Round 10
// baseline (2872.465 us; speedup 1.0000x reference)
//
#include <hip/hip_runtime.h>

#define K_IN   256
#define N_OUT  128
#define BM     32
#define SCAN_CHUNK 1024
#define NBLK   512        // hist/scatter partition width
#define BSHIFT 7
#define BNODES 128        // dst nodes per bucket
#define CAP    8192       // record capacity of LDS sort buffer (64 KB)
#define NKEY   2048       // sort bins: (srcWin<<7) | dstLow
#define WSHIFT 13         // src window = 8192 rows = 2 MB of hb

typedef short bf16x8 __attribute__((ext_vector_type(8)));
typedef float f32x4  __attribute__((ext_vector_type(4)));

static __device__ __forceinline__ unsigned short f2bf(float f) {
    unsigned u = __float_as_uint(f);
    unsigned r = (u + 0x7FFF + ((u >> 16) & 1)) >> 16;   // RNE
    return (unsigned short)r;
}
static __device__ __forceinline__ float bf2f(unsigned short b) {
    return __uint_as_float(((unsigned)b) << 16);
}

// Hardware LDS float atomic-add. NO "memory" clobber: round 9 showed the
// clobber serializes the surrounding loads (each record paid full L2 latency
// -> 23x slowdown). Ordering vs the epilogue reads is provided by
// __syncthreads() (lgkmcnt(0) drain + barrier + compiler fence).
static __device__ __forceinline__ void lds_fadd(float* p, float v) {
    const unsigned off = (unsigned)(unsigned long long)p;
    asm volatile("ds_add_f32 %0, %1" :: "v"(off), "v"(v));
}

// ---- prep: W[256][128] fp32 -> pre-swizzled bf16 image WbT[n=128][k=256] (64KB)
__global__ __launch_bounds__(256) void prep_w(const float* __restrict__ W, char* __restrict__ wbt)
{
    const int t = blockIdx.x * 256 + threadIdx.x;
    if (t >= N_OUT * 32) return;
    const int n = t >> 5;
    const int c = t & 31;
    unsigned v[4];
#pragma unroll
    for (int p = 0; p < 4; ++p) {
        const unsigned lo = f2bf(W[(size_t)(c * 8 + 2 * p)     * N_OUT + n]);
        const unsigned hi = f2bf(W[(size_t)(c * 8 + 2 * p + 1) * N_OUT + n]);
        v[p] = lo | (hi << 16);
    }
    const int byte = n * 512 + ((c * 16) ^ ((n & 7) << 4));
    *reinterpret_cast<uint4*>(wbt + byte) = make_uint4(v[0], v[1], v[2], v[3]);
}

// ---- GEMM (bf16 MFMA) + fused dst-histogram in blocks 0..NBLK-1
__global__ __launch_bounds__(256) void gcn_gemm(
    const float* __restrict__ x, const uint4* __restrict__ wbt,
    const float* __restrict__ bias, unsigned short* __restrict__ hb,
    const int* __restrict__ ei, int* __restrict__ histG,
    int M, int E, int B, int chunk)
{
    __shared__ uint4 smem4[81920 / 16];
    char* smem = (char*)smem4;
    const int tid  = threadIdx.x;
    const int row0 = blockIdx.x * BM;

    {
        uint4* wl = (uint4*)smem;
#pragma unroll
        for (int it = 0; it < 16; ++it) wl[it * 256 + tid] = wbt[it * 256 + tid];
    }
    {
        const int r    = tid >> 3;
        const int ks   = tid & 7;
        const int grow = row0 + r;
        char* xbase    = smem + 65536 + r * 512;
        const int swz  = (r & 7) << 4;
        if (grow < M) {
            const float4* src = reinterpret_cast<const float4*>(x + (size_t)grow * K_IN + ks * 32);
#pragma unroll
            for (int q = 0; q < 8; ++q) {
                const float4 f = src[q];
                uint2 v;
                v.x = (unsigned)f2bf(f.x) | ((unsigned)f2bf(f.y) << 16);
                v.y = (unsigned)f2bf(f.z) | ((unsigned)f2bf(f.w) << 16);
                const int kb = ks * 64 + q * 8;
                *reinterpret_cast<uint2*>(xbase + (((kb & ~15) ^ swz) | (kb & 15))) = v;
            }
        } else {
            const uint2 z = make_uint2(0u, 0u);
#pragma unroll
            for (int q = 0; q < 8; ++q) {
                const int kb = ks * 64 + q * 8;
                *reinterpret_cast<uint2*>(xbase + (((kb & ~15) ^ swz) | (kb & 15))) = z;
            }
        }
    }
    __syncthreads();

    const int lane = tid & 63;
    const int wv   = tid >> 6;
    const int wr   = wv >> 1;
    const int wc   = wv & 1;
    const int l15  = lane & 15;
    const int lk   = lane >> 4;

    const int  arow = wr * 16 + l15;
    const char* xrow = smem + 65536 + arow * 512;
    const int  aswz = (arow & 7) << 4;
    const int  bswz = (l15 & 7) << 4;
    const char* brow0 = smem + (size_t)(wc * 64 + l15) * 512;

    f32x4 acc[4] = {};

#pragma unroll
    for (int ks = 0; ks < 8; ++ks) {
        const int kb = ks * 64 + lk * 16;
        const bf16x8 a = *reinterpret_cast<const bf16x8*>(xrow + (kb ^ aswz));
        const int bk = kb ^ bswz;
#pragma unroll
        for (int j = 0; j < 4; ++j) {
            const bf16x8 b = *reinterpret_cast<const bf16x8*>(brow0 + j * (16 * 512) + bk);
            acc[j] = __builtin_amdgcn_mfma_f32_16x16x32_bf16(a, b, acc[j], 0, 0, 0);
        }
    }

#pragma unroll
    for (int j = 0; j < 4; ++j) {
        const int gcol = wc * 64 + j * 16 + l15;
        const float bv = bias[gcol];
#pragma unroll
        for (int r = 0; r < 4; ++r) {
            const int grow = row0 + wr * 16 + lk * 4 + r;
            if (grow < M)
                hb[(size_t)grow * N_OUT + gcol] = f2bf(acc[j][r] + bv);
        }
    }

    // ---- fused histogram (blocks 0..NBLK-1), reusing LDS after the GEMM phase
    if (blockIdx.x < NBLK) {
        __syncthreads();
        int* bins = (int*)smem;
        for (int i = tid; i < B; i += 256) bins[i] = 0;
        __syncthreads();
        const int beg = blockIdx.x * chunk;
        const int end = min(beg + chunk, E);
        for (int i = beg + tid; i < end; i += 256)
            atomicAdd(&bins[ei[i] >> BSHIFT], 1);
        __syncthreads();
        for (int i = tid; i < B; i += 256) histG[i * NBLK + blockIdx.x] = bins[i];
    }
}

// ---- scans over n = B*NBLK entries ----
__global__ __launch_bounds__(256) void scan_block_sums(
    const int* __restrict__ cnt, int n, int* __restrict__ bsum)
{
    __shared__ int sd[256];
    const int base = blockIdx.x * SCAN_CHUNK + threadIdx.x * 4;
    int s = 0;
#pragma unroll
    for (int j = 0; j < 4; ++j) { const int idx = base + j; if (idx < n) s += cnt[idx]; }
    sd[threadIdx.x] = s; __syncthreads();
    for (int off = 128; off > 0; off >>= 1) {
        if (threadIdx.x < off) sd[threadIdx.x] += sd[threadIdx.x + off];
        __syncthreads();
    }
    if (threadIdx.x == 0) bsum[blockIdx.x] = sd[0];
}

__global__ __launch_bounds__(1024) void scan_sums(
    int* __restrict__ bsum, int nb, int* __restrict__ P, int n)
{
    __shared__ int sd[1024];
    const int t = threadIdx.x;
    const int v = (t < nb) ? bsum[t] : 0;
    sd[t] = v; __syncthreads();
    for (int off = 1; off < 1024; off <<= 1) {
        const int add = (t >= off) ? sd[t - off] : 0;
        __syncthreads();
        sd[t] += add;
        __syncthreads();
    }
    if (t < nb) bsum[t] = sd[t] - v;
    if (t == nb - 1) P[n] = sd[t];
}

__global__ __launch_bounds__(256) void scan_write_offsets(
    const int* __restrict__ cnt, int n, const int* __restrict__ bsum, int* __restrict__ P)
{
    __shared__ int sd[256];
    const int t = threadIdx.x;
    const int base = blockIdx.x * SCAN_CHUNK + t * 4;
    int v[4]; int s = 0;
#pragma unroll
    for (int j = 0; j < 4; ++j) { const int idx = base + j; v[j] = (idx < n) ? cnt[idx] : 0; s += v[j]; }
    sd[t] = s; __syncthreads();
    const int own = s;
    for (int off = 1; off < 256; off <<= 1) {
        const int add = (t >= off) ? sd[t - off] : 0;
        __syncthreads();
        sd[t] += add;
        __syncthreads();
    }
    int run = bsum[blockIdx.x] + (sd[t] - own);
#pragma unroll
    for (int j = 0; j < 4; ++j) {
        const int idx = base + j;
        if (idx < n) { P[idx] = run; run += v[j]; }
    }
}

// ---- Pass B: place records into private per-(bucket,block) regions
__global__ __launch_bounds__(256) void scatter_records(
    const int* __restrict__ ei, const float* __restrict__ ew, int E, int M, int B,
    const int* __restrict__ P, uint2* __restrict__ rec, int chunk)
{
    __shared__ int cur[1024];
    for (int i = threadIdx.x; i < B; i += 256) cur[i] = P[i * NBLK + blockIdx.x];
    __syncthreads();
    const int beg = blockIdx.x * chunk;
    const int end = min(beg + chunk, E);
    for (int i = beg + threadIdx.x; i < end; i += 256) {
        const int d = ei[i];
        const int s = ei[(size_t)E + i];
        const int pos = atomicAdd(&cur[d >> BSHIFT], 1);
        rec[pos] = make_uint2((unsigned)s | ((unsigned)(d & (BNODES - 1)) << 24),
                              __float_as_uint(ew[i]));
    }
}

// ---- Pass C: per-bucket in-place counting sort, WINDOW-MAJOR key:
// key = (srcWin<<7) | dstLow -> window-w records are one contiguous segment.
// Emits offW[b][0..16] = segment starts.
__global__ __launch_bounds__(256) void sort_bucket(
    const int* __restrict__ P, uint2* __restrict__ rec,
    int* __restrict__ offW, int* __restrict__ bflag, int M, int B)
{
    __shared__ uint2 srt[CAP];          // 64 KB staging
    __shared__ int hist[NKEY];          // 8 KB: counts -> prefix -> cursors
    __shared__ int sd[256];

    const int b   = blockIdx.x;
    const int tid = threadIdx.x;
    const int beg = P[b * NBLK];
    const int end = P[(b + 1) * NBLK];
    const int cnt = end - beg;

    for (int i = tid; i < NKEY; i += 256) hist[i] = 0;
    if (tid == 0) bflag[b] = (cnt <= CAP) ? 0 : 1;
    __syncthreads();

    if (cnt > CAP) return;   // aggregate falls back to unsorted single segment

    // stage + histogram by 11-bit window-major key
    for (int i = beg + tid; i < end; i += 256) {
        const uint2 r = rec[i];
        srt[i - beg] = r;
        const int key = (int)((((r.x & 0xFFFFFF) >> WSHIFT) << 7) | (r.x >> 24));
        atomicAdd(&hist[key], 1);
    }
    __syncthreads();

    // in-place exclusive scan of hist[NKEY]: 8 bins per thread
    const int base = tid * 8;
    int v[8]; int s = 0;
#pragma unroll
    for (int j = 0; j < 8; ++j) { v[j] = hist[base + j]; s += v[j]; }
    sd[tid] = s; __syncthreads();
    for (int off = 1; off < 256; off <<= 1) {
        const int add = (tid >= off) ? sd[tid - off] : 0;
        __syncthreads();
        sd[tid] += add;
        __syncthreads();
    }
    int run = sd[tid] - s;
#pragma unroll
    for (int j = 0; j < 8; ++j) { hist[base + j] = run; run += v[j]; }
    __syncthreads();

    // per-window segment starts (hist holds exclusive prefix here)
    if (tid <= 16)
        offW[b * 17 + tid] = beg + ((tid < 16) ? hist[tid << 7] : cnt);
    __syncthreads();

    // scatter back in place, sorted by key (hist doubles as cursor array)
    for (int i = tid; i < cnt; i += 256) {
        const uint2 r = srt[i];
        const int key = (int)((((r.x & 0xFFFFFF) >> WSHIFT) << 7) | (r.x >> 24));
        const int pos = atomicAdd(&hist[key], 1);
        rec[beg + pos] = r;
    }
}

// ---- Aggregate: block = bucket, 512 thr, split-plane LDS accumulators
// accX[128][64] / accY[128][64]. Inner loop hand-batched: 8 record loads +
// 8 hb-row loads into registers FIRST (16-deep MLP), then 16 ds_add_f32.
__global__ __launch_bounds__(512) void aggregate2(
    const int* __restrict__ offW, const int* __restrict__ P,
    const int* __restrict__ bflag, const uint2* __restrict__ rec,
    const unsigned short* __restrict__ hb, float* __restrict__ out,
    int M, int nwin)
{
    __shared__ float acc[BNODES * N_OUT];   // 64 KB: [0,8K)=X plane, [8K,16K)=Y plane
    float* accX = acc;
    float* accY = acc + BNODES * 64;
    const int b    = blockIdx.x;
    const int tid  = threadIdx.x;
    const int lane = tid & 63;
    const int wv   = tid >> 6;              // 0..7
    const unsigned* __restrict__ hb32 = reinterpret_cast<const unsigned*>(hb);

    for (int i = tid; i < BNODES * N_OUT; i += 512) acc[i] = 0.f;
    __syncthreads();

    const int sorted = (bflag[b] == 0);
    const int nseg = sorted ? nwin : 1;
    for (int seg = 0; seg < nseg; ++seg) {
        int s, e;
        if (sorted) { s = offW[b * 17 + seg]; e = offW[b * 17 + seg + 1]; }
        else        { s = P[b * NBLK];        e = P[(b + 1) * NBLK]; }
        // 8 waves x 8-record batches, stride 64
        for (int i = s + wv * 8; i < e; i += 64) {
            float    wq[8];
            unsigned uq[8];
            int      dq[8];
#pragma unroll
            for (int q = 0; q < 8; ++q) {
                const int oob = (i + q >= e);
                const int ii  = oob ? s : (i + q);     // clamped, always valid
                const uint2 r = rec[ii];
                wq[q] = oob ? 0.f : __uint_as_float(r.y);
                dq[q] = oob ? 0   : (int)(r.x >> 24);
                uq[q] = oob ? 0u  : hb32[(size_t)((r.x & 0xFFFFFF) << 6) + lane];
            }
#pragma unroll
            for (int q = 0; q < 8; ++q) {
                lds_fadd(&accX[dq[q] * 64 + lane], wq[q] * bf2f((unsigned short)uq[q]));
                lds_fadd(&accY[dq[q] * 64 + lane], wq[q] * bf2f((unsigned short)(uq[q] >> 16)));
            }
        }
        __syncthreads();   // keep block's waves window-aligned for the convoy
    }

    // epilogue: coalesced LDS -> out; feature 2c from X plane, 2c+1 from Y
    const int node0 = b << BSHIFT;
    for (int idx = tid; idx < BNODES * 64; idx += 512) {
        const int nn = idx >> 6;
        const int c  = idx & 63;
        const int node = node0 + nn;
        if (node < M)
            reinterpret_cast<float2*>(out + (size_t)node * N_OUT)[c] =
                make_float2(accX[nn * 64 + c], accY[nn * 64 + c]);
    }
}

extern "C" void kernel_launch(void* const* d_in, const int* in_sizes, int n_in,
                              void* d_out, int out_size, void* d_ws, size_t ws_size,
                              hipStream_t stream)
{
    const float* x    = (const float*)d_in[0];
    const int*   ei   = (const int*)d_in[1];
    const float* ew   = (const float*)d_in[2];
    const float* W    = (const float*)d_in[3];
    const float* bias = (const float*)d_in[4];
    float* out = (float*)d_out;

    const int M = in_sizes[0] / K_IN;   // 100000
    const int E = in_sizes[1] / 2;      // 3200000
    const int B = (M + BNODES - 1) >> BSHIFT;          // 782
    const int n = B * NBLK;                             // 400384
    const int nb = (n + SCAN_CHUNK - 1) / SCAN_CHUNK;   // 391
    const int chunk = (E + NBLK - 1) / NBLK;            // 6250
    const int nwin = (M + (1 << WSHIFT) - 1) >> WSHIFT; // 13

    auto align256 = [](size_t v) { return (v + 255) & ~(size_t)255; };
    const size_t o_hb    = 0;
    const size_t o_hist  = align256(o_hb + (size_t)M * N_OUT * sizeof(unsigned short));
    const size_t o_P     = align256(o_hist + (size_t)n * sizeof(int));
    const size_t o_bsum  = align256(o_P + (size_t)(n + 1) * sizeof(int));
    const size_t o_offW  = align256(o_bsum + (size_t)1024 * sizeof(int));
    const size_t o_bflag = align256(o_offW + (size_t)B * 17 * sizeof(int));
    const size_t o_wbt   = align256(o_bflag + (size_t)B * sizeof(int));
    const size_t o_rec   = align256(o_wbt + (size_t)65536);

    unsigned short* hb    = (unsigned short*)((char*)d_ws + o_hb);
    int*            histG = (int*)((char*)d_ws + o_hist);
    int*            P     = (int*)((char*)d_ws + o_P);
    int*            bsum  = (int*)((char*)d_ws + o_bsum);
    int*            offW  = (int*)((char*)d_ws + o_offW);
    int*            bflag = (int*)((char*)d_ws + o_bflag);
    char*           wbt   = (char*)d_ws + o_wbt;
    uint2*          rec   = (uint2*)((char*)d_ws + o_rec);

    prep_w<<<16, 256, 0, stream>>>(W, wbt);
    gcn_gemm<<<(M + BM - 1) / BM, 256, 0, stream>>>(
        x, (const uint4*)wbt, bias, hb, ei, histG, M, E, B, chunk);
    scan_block_sums<<<nb, 256, 0, stream>>>(histG, n, bsum);
    scan_sums<<<1, 1024, 0, stream>>>(bsum, nb, P, n);
    scan_write_offsets<<<nb, 256, 0, stream>>>(histG, n, bsum, P);
    scatter_records<<<NBLK, 256, 0, stream>>>(ei, ew, E, M, B, P, rec, chunk);
    sort_bucket<<<B, 256, 0, stream>>>(P, rec, offW, bflag, M, B);
    aggregate2<<<B, 512, 0, stream>>>(offW, P, bflag, rec, hb, out, M, nwin);
}

// Round 11
// 251.963 us; speedup vs baseline: 11.4004x; 11.4004x over previous
//
#include <hip/hip_runtime.h>

#define K_IN   256
#define N_OUT  128
#define BM     32
#define SCAN_CHUNK 1024
#define NBLK   512        // hist/scatter partition width
#define BSHIFT 7
#define BNODES 128        // dst nodes per bucket
#define CAP    8192       // record capacity of LDS sort buffer (64 KB)
#define NKEY   2048       // sort bins: (dstLow<<4) | (src>>13)

typedef short bf16x8 __attribute__((ext_vector_type(8)));
typedef float f32x4  __attribute__((ext_vector_type(4)));

static __device__ __forceinline__ unsigned short f2bf(float f) {
    unsigned u = __float_as_uint(f);
    unsigned r = (u + 0x7FFF + ((u >> 16) & 1)) >> 16;   // RNE
    return (unsigned short)r;
}
static __device__ __forceinline__ float bf2f(unsigned short b) {
    return __uint_as_float(((unsigned)b) << 16);
}

// ---- prep: W[256][128] fp32 -> pre-swizzled bf16 image WbT[n=128][k=256] (64KB)
__global__ __launch_bounds__(256) void prep_w(const float* __restrict__ W, char* __restrict__ wbt)
{
    const int t = blockIdx.x * 256 + threadIdx.x;
    if (t >= N_OUT * 32) return;
    const int n = t >> 5;
    const int c = t & 31;
    unsigned v[4];
#pragma unroll
    for (int p = 0; p < 4; ++p) {
        const unsigned lo = f2bf(W[(size_t)(c * 8 + 2 * p)     * N_OUT + n]);
        const unsigned hi = f2bf(W[(size_t)(c * 8 + 2 * p + 1) * N_OUT + n]);
        v[p] = lo | (hi << 16);
    }
    const int byte = n * 512 + ((c * 16) ^ ((n & 7) << 4));
    *reinterpret_cast<uint4*>(wbt + byte) = make_uint4(v[0], v[1], v[2], v[3]);
}

// ---- GEMM (bf16 MFMA) + fused dst-histogram in blocks 0..NBLK-1
__global__ __launch_bounds__(256) void gcn_gemm(
    const float* __restrict__ x, const uint4* __restrict__ wbt,
    const float* __restrict__ bias, unsigned short* __restrict__ hb,
    const int* __restrict__ ei, int* __restrict__ histG,
    int M, int E, int B, int chunk)
{
    __shared__ uint4 smem4[81920 / 16];
    char* smem = (char*)smem4;
    const int tid  = threadIdx.x;
    const int row0 = blockIdx.x * BM;

    {
        uint4* wl = (uint4*)smem;
#pragma unroll
        for (int it = 0; it < 16; ++it) wl[it * 256 + tid] = wbt[it * 256 + tid];
    }
    {
        const int r    = tid >> 3;
        const int ks   = tid & 7;
        const int grow = row0 + r;
        char* xbase    = smem + 65536 + r * 512;
        const int swz  = (r & 7) << 4;
        if (grow < M) {
            const float4* src = reinterpret_cast<const float4*>(x + (size_t)grow * K_IN + ks * 32);
#pragma unroll
            for (int q = 0; q < 8; ++q) {
                const float4 f = src[q];
                uint2 v;
                v.x = (unsigned)f2bf(f.x) | ((unsigned)f2bf(f.y) << 16);
                v.y = (unsigned)f2bf(f.z) | ((unsigned)f2bf(f.w) << 16);
                const int kb = ks * 64 + q * 8;
                *reinterpret_cast<uint2*>(xbase + (((kb & ~15) ^ swz) | (kb & 15))) = v;
            }
        } else {
            const uint2 z = make_uint2(0u, 0u);
#pragma unroll
            for (int q = 0; q < 8; ++q) {
                const int kb = ks * 64 + q * 8;
                *reinterpret_cast<uint2*>(xbase + (((kb & ~15) ^ swz) | (kb & 15))) = z;
            }
        }
    }
    __syncthreads();

    const int lane = tid & 63;
    const int wv   = tid >> 6;
    const int wr   = wv >> 1;
    const int wc   = wv & 1;
    const int l15  = lane & 15;
    const int lk   = lane >> 4;

    const int  arow = wr * 16 + l15;
    const char* xrow = smem + 65536 + arow * 512;
    const int  aswz = (arow & 7) << 4;
    const int  bswz = (l15 & 7) << 4;
    const char* brow0 = smem + (size_t)(wc * 64 + l15) * 512;

    f32x4 acc[4] = {};

#pragma unroll
    for (int ks = 0; ks < 8; ++ks) {
        const int kb = ks * 64 + lk * 16;
        const bf16x8 a = *reinterpret_cast<const bf16x8*>(xrow + (kb ^ aswz));
        const int bk = kb ^ bswz;
#pragma unroll
        for (int j = 0; j < 4; ++j) {
            const bf16x8 b = *reinterpret_cast<const bf16x8*>(brow0 + j * (16 * 512) + bk);
            acc[j] = __builtin_amdgcn_mfma_f32_16x16x32_bf16(a, b, acc[j], 0, 0, 0);
        }
    }

#pragma unroll
    for (int j = 0; j < 4; ++j) {
        const int gcol = wc * 64 + j * 16 + l15;
        const float bv = bias[gcol];
#pragma unroll
        for (int r = 0; r < 4; ++r) {
            const int grow = row0 + wr * 16 + lk * 4 + r;
            if (grow < M)
                hb[(size_t)grow * N_OUT + gcol] = f2bf(acc[j][r] + bv);
        }
    }

    // ---- fused histogram (blocks 0..NBLK-1), reusing LDS after the GEMM phase
    if (blockIdx.x < NBLK) {
        __syncthreads();
        int* bins = (int*)smem;
        for (int i = tid; i < B; i += 256) bins[i] = 0;
        __syncthreads();
        const int beg = blockIdx.x * chunk;
        const int end = min(beg + chunk, E);
        for (int i = beg + tid; i < end; i += 256)
            atomicAdd(&bins[ei[i] >> BSHIFT], 1);
        __syncthreads();
        for (int i = tid; i < B; i += 256) histG[i * NBLK + blockIdx.x] = bins[i];
    }
}

// ---- scans over n = B*NBLK entries ----
__global__ __launch_bounds__(256) void scan_block_sums(
    const int* __restrict__ cnt, int n, int* __restrict__ bsum)
{
    __shared__ int sd[256];
    const int base = blockIdx.x * SCAN_CHUNK + threadIdx.x * 4;
    int s = 0;
#pragma unroll
    for (int j = 0; j < 4; ++j) { const int idx = base + j; if (idx < n) s += cnt[idx]; }
    sd[threadIdx.x] = s; __syncthreads();
    for (int off = 128; off > 0; off >>= 1) {
        if (threadIdx.x < off) sd[threadIdx.x] += sd[threadIdx.x + off];
        __syncthreads();
    }
    if (threadIdx.x == 0) bsum[blockIdx.x] = sd[0];
}

__global__ __launch_bounds__(1024) void scan_sums(
    int* __restrict__ bsum, int nb, int* __restrict__ P, int n)
{
    __shared__ int sd[1024];
    const int t = threadIdx.x;
    const int v = (t < nb) ? bsum[t] : 0;
    sd[t] = v; __syncthreads();
    for (int off = 1; off < 1024; off <<= 1) {
        const int add = (t >= off) ? sd[t - off] : 0;
        __syncthreads();
        sd[t] += add;
        __syncthreads();
    }
    if (t < nb) bsum[t] = sd[t] - v;
    if (t == nb - 1) P[n] = sd[t];
}

__global__ __launch_bounds__(256) void scan_write_offsets(
    const int* __restrict__ cnt, int n, const int* __restrict__ bsum, int* __restrict__ P)
{
    __shared__ int sd[256];
    const int t = threadIdx.x;
    const int base = blockIdx.x * SCAN_CHUNK + t * 4;
    int v[4]; int s = 0;
#pragma unroll
    for (int j = 0; j < 4; ++j) { const int idx = base + j; v[j] = (idx < n) ? cnt[idx] : 0; s += v[j]; }
    sd[t] = s; __syncthreads();
    const int own = s;
    for (int off = 1; off < 256; off <<= 1) {
        const int add = (t >= off) ? sd[t - off] : 0;
        __syncthreads();
        sd[t] += add;
        __syncthreads();
    }
    int run = bsum[blockIdx.x] + (sd[t] - own);
#pragma unroll
    for (int j = 0; j < 4; ++j) {
        const int idx = base + j;
        if (idx < n) { P[idx] = run; run += v[j]; }
    }
}

// ---- Pass B: place records into private per-(bucket,block) regions
__global__ __launch_bounds__(256) void scatter_records(
    const int* __restrict__ ei, const float* __restrict__ ew, int E, int M, int B,
    const int* __restrict__ P, uint2* __restrict__ rec, int chunk)
{
    __shared__ int cur[1024];
    for (int i = threadIdx.x; i < B; i += 256) cur[i] = P[i * NBLK + blockIdx.x];
    __syncthreads();
    const int beg = blockIdx.x * chunk;
    const int end = min(beg + chunk, E);
    for (int i = beg + threadIdx.x; i < end; i += 256) {
        const int d = ei[i];
        const int s = ei[(size_t)E + i];
        const int pos = atomicAdd(&cur[d >> BSHIFT], 1);
        rec[pos] = make_uint2((unsigned)s | ((unsigned)(d & (BNODES - 1)) << 24),
                              __float_as_uint(ew[i]));
    }
}

// ---- Pass C: per-bucket in-place counting sort by (dstLow, srcWindow) key
// key = (dstLow<<4) | (src>>13): stable grouping by node, then 2MB src window
__global__ __launch_bounds__(256) void sort_bucket(
    const int* __restrict__ P, uint2* __restrict__ rec,
    int* __restrict__ offsN, int* __restrict__ bflag, int M, int B)
{
    __shared__ uint2 srt[CAP];          // 64 KB staging
    __shared__ int hist[NKEY];          // 8 KB: counts -> exclusive prefix -> cursors
    __shared__ int sd[256];

    const int b   = blockIdx.x;
    const int tid = threadIdx.x;
    const int beg = P[b * NBLK];
    const int end = P[(b + 1) * NBLK];
    const int cnt = end - beg;
    const int node0 = b << BSHIFT;

    for (int i = tid; i < NKEY; i += 256) hist[i] = 0;
    if (tid == 0) bflag[b] = (cnt <= CAP) ? 0 : 1;
    if (tid == 0 && b == B - 1) offsN[M] = end;
    __syncthreads();

    if (cnt > CAP) {
        // statistically unreachable: gather scans-and-filters this bucket
        if (tid < BNODES) {
            const int node = node0 + tid;
            if (node < M) offsN[node] = beg;
        }
        return;
    }

    // stage + histogram by 11-bit key
    for (int i = beg + tid; i < end; i += 256) {
        const uint2 r = rec[i];
        srt[i - beg] = r;
        const int key = ((r.x >> 24) << 4) | ((r.x & 0xFFFFFF) >> 13);
        atomicAdd(&hist[key], 1);
    }
    __syncthreads();

    // in-place exclusive scan of hist[NKEY]: 8 bins per thread
    const int base = tid * 8;
    int v[8]; int s = 0;
#pragma unroll
    for (int j = 0; j < 8; ++j) { v[j] = hist[base + j]; s += v[j]; }
    sd[tid] = s; __syncthreads();
    for (int off = 1; off < 256; off <<= 1) {
        const int add = (tid >= off) ? sd[tid - off] : 0;
        __syncthreads();
        sd[tid] += add;
        __syncthreads();
    }
    int run = sd[tid] - s;   // exclusive base for this thread's 8 bins
#pragma unroll
    for (int j = 0; j < 8; ++j) { hist[base + j] = run; run += v[j]; }
    __syncthreads();

    // per-node offsets = beg + excl at key (dstLow<<4)
    if (tid < BNODES) {
        const int node = node0 + tid;
        if (node < M) offsN[node] = beg + hist[tid << 4];
    }
    __syncthreads();

    // scatter back in place, sorted by key (hist doubles as cursor array)
    for (int i = tid; i < cnt; i += 256) {
        const uint2 r = srt[i];
        const int key = ((r.x >> 24) << 4) | ((r.x & 0xFFFFFF) >> 13);
        const int pos = atomicAdd(&hist[key], 1);
        rec[beg + pos] = r;
    }
}

// ---- Gather: one wave per node; lane owns feat pair; 16-deep batched loads
// (halves the dependent batch round-trips vs round 6's 8-deep; latency-bound)
__global__ __launch_bounds__(256) void gather_kernel(
    const int* __restrict__ offsN, const int* __restrict__ P,
    const int* __restrict__ bflag, const uint2* __restrict__ rec,
    const unsigned short* __restrict__ hb, float* __restrict__ out, int M)
{
    const int n = blockIdx.x * 4 + (threadIdx.x >> 6);
    if (n >= M) return;
    const int lane = threadIdx.x & 63;
    const int b = n >> BSHIFT;
    const unsigned* __restrict__ hb32 = reinterpret_cast<const unsigned*>(hb);

    float ax = 0.f, ay = 0.f;

    if (bflag[b] == 0) {
        const int beg = offsN[n], end = offsN[n + 1];
        int i = beg;
        for (; i + 16 <= end; i += 16) {
            unsigned u[16]; float w[16];
#pragma unroll
            for (int q = 0; q < 16; ++q) {
                const uint2 r = rec[i + q];
                w[q] = __uint_as_float(r.y);
                u[q] = hb32[(size_t)((r.x & 0xFFFFFF) << 6) + lane];
            }
#pragma unroll
            for (int q = 0; q < 16; ++q) {
                ax += w[q] * bf2f((unsigned short)u[q]);
                ay += w[q] * bf2f((unsigned short)(u[q] >> 16));
            }
        }
        for (; i + 8 <= end; i += 8) {
            unsigned u[8]; float w[8];
#pragma unroll
            for (int q = 0; q < 8; ++q) {
                const uint2 r = rec[i + q];
                w[q] = __uint_as_float(r.y);
                u[q] = hb32[(size_t)((r.x & 0xFFFFFF) << 6) + lane];
            }
#pragma unroll
            for (int q = 0; q < 8; ++q) {
                ax += w[q] * bf2f((unsigned short)u[q]);
                ay += w[q] * bf2f((unsigned short)(u[q] >> 16));
            }
        }
        for (; i < end; ++i) {
            const uint2 r = rec[i];
            const float w = __uint_as_float(r.y);
            const unsigned u = hb32[(size_t)((r.x & 0xFFFFFF) << 6) + lane];
            ax += w * bf2f((unsigned short)u);
            ay += w * bf2f((unsigned short)(u >> 16));
        }
    } else {
        // unsorted bucket: scan and filter (statistically unreachable)
        const int beg = P[b * NBLK], end = P[(b + 1) * NBLK];
        const unsigned want = (unsigned)(n & (BNODES - 1));
        for (int i = beg; i < end; ++i) {
            const uint2 r = rec[i];
            if ((r.x >> 24) != want) continue;
            const float w = __uint_as_float(r.y);
            const unsigned u = hb32[(size_t)((r.x & 0xFFFFFF) << 6) + lane];
            ax += w * bf2f((unsigned short)u);
            ay += w * bf2f((unsigned short)(u >> 16));
        }
    }

    reinterpret_cast<float2*>(out + (size_t)n * N_OUT)[lane] = make_float2(ax, ay);
}

extern "C" void kernel_launch(void* const* d_in, const int* in_sizes, int n_in,
                              void* d_out, int out_size, void* d_ws, size_t ws_size,
                              hipStream_t stream)
{
    const float* x    = (const float*)d_in[0];
    const int*   ei   = (const int*)d_in[1];
    const float* ew   = (const float*)d_in[2];
    const float* W    = (const float*)d_in[3];
    const float* bias = (const float*)d_in[4];
    float* out = (float*)d_out;

    const int M = in_sizes[0] / K_IN;   // 100000
    const int E = in_sizes[1] / 2;      // 3200000
    const int B = (M + BNODES - 1) >> BSHIFT;          // 782
    const int n = B * NBLK;                             // 400384
    const int nb = (n + SCAN_CHUNK - 1) / SCAN_CHUNK;   // 391
    const int chunk = (E + NBLK - 1) / NBLK;            // 6250

    auto align256 = [](size_t v) { return (v + 255) & ~(size_t)255; };
    const size_t o_hb    = 0;
    const size_t o_hist  = align256(o_hb + (size_t)M * N_OUT * sizeof(unsigned short));
    const size_t o_P     = align256(o_hist + (size_t)n * sizeof(int));
    const size_t o_bsum  = align256(o_P + (size_t)(n + 1) * sizeof(int));
    const size_t o_offsN = align256(o_bsum + (size_t)1024 * sizeof(int));
    const size_t o_bflag = align256(o_offsN + (size_t)(M + 1) * sizeof(int));
    const size_t o_wbt   = align256(o_bflag + (size_t)B * sizeof(int));
    const size_t o_rec   = align256(o_wbt + (size_t)65536);

    unsigned short* hb    = (unsigned short*)((char*)d_ws + o_hb);
    int*            histG = (int*)((char*)d_ws + o_hist);
    int*            P     = (int*)((char*)d_ws + o_P);
    int*            bsum  = (int*)((char*)d_ws + o_bsum);
    int*            offsN = (int*)((char*)d_ws + o_offsN);
    int*            bflag = (int*)((char*)d_ws + o_bflag);
    char*           wbt   = (char*)d_ws + o_wbt;
    uint2*          rec   = (uint2*)((char*)d_ws + o_rec);

    prep_w<<<16, 256, 0, stream>>>(W, wbt);
    gcn_gemm<<<(M + BM - 1) / BM, 256, 0, stream>>>(
        x, (const uint4*)wbt, bias, hb, ei, histG, M, E, B, chunk);
    scan_block_sums<<<nb, 256, 0, stream>>>(histG, n, bsum);
    scan_sums<<<1, 1024, 0, stream>>>(bsum, nb, P, n);
    scan_write_offsets<<<nb, 256, 0, stream>>>(histG, n, bsum, P);
    scatter_records<<<NBLK, 256, 0, stream>>>(ei, ew, E, M, B, P, rec, chunk);
    sort_bucket<<<B, 256, 0, stream>>>(P, rec, offsN, bflag, M, B);
    gather_kernel<<<(M + 3) / 4, 256, 0, stream>>>(offsN, P, bflag, rec, hb, out, M);
}